// Round 13
// baseline (676.733 us; speedup 1.0000x reference)
//
#include <hip/hip_runtime.h>

// Problem constants (fixed by the reference file)
#define NND 50000   // nodes
#define NE  600000  // edges
#define TSEQ 50     // sequence length
#define NB  1000    // batch = NND/TSEQ
#define SB  4       // sequences per LSTM workgroup (250 WGs ~= 1/CU)
                    // NOTE: M=16 MFMA tile => per-WG cost invariant in SB.
                    // SB=16: 63 WGs (141us), SB=4: 250 WGs (88.6us), SB=2:
                    // 500 WGs = 2x total MFMA work (147.6us, R11 regression).
#define AHS 136     // LDS h-row stride in shorts (128 + 8 pad, 16B-aligned)
#define NSCB 196    // scan blocks: ceil(NND/256)
#define CHK 10      // G-load / H-store chunk (TSEQ must be divisible)

typedef __attribute__((ext_vector_type(4))) float f32x4;
typedef __attribute__((ext_vector_type(8))) short s16x8;

// ---------------------------------------------------------------- helpers
__device__ __forceinline__ float sigf(float x) {
    return 1.0f / (1.0f + __expf(-x));
}
__device__ __forceinline__ float tanhfast(float x) {
    x = fminf(fmaxf(x, -15.f), 15.f);
    float e = __expf(2.f * x);
    return (e - 1.f) / (e + 1.f);
}
// bf16 bit helpers (round-to-nearest-even)
__device__ __forceinline__ unsigned short f2bf(float f) {
    unsigned int u = __float_as_uint(f);
    u = u + 0x7FFFu + ((u >> 16) & 1u);
    return (unsigned short)(u >> 16);
}
__device__ __forceinline__ float bf2f(unsigned short h) {
    return __uint_as_float(((unsigned int)h) << 16);
}

// ---------------------------------------------------------------- CSR build
__global__ void k_count(const int* __restrict__ ei, int* __restrict__ cnt) {
    int e = blockIdx.x * 256 + threadIdx.x;
    if (e < NE) atomicAdd(&cnt[ei[NE + e]], 1);
}

__global__ void k_dinv(const int* __restrict__ cnt, float* __restrict__ dinv) {
    int i = blockIdx.x * 256 + threadIdx.x;
    if (i < NND) dinv[i] = 1.0f / sqrtf((float)cnt[i] + 1.0f);
}

// ---- 3-stage multi-block exclusive scan of cnt -> rowstart
__global__ __launch_bounds__(256) void k_bsum(const int* __restrict__ cnt,
                                              int* __restrict__ bsum) {
    __shared__ int red[256];
    int t = threadIdx.x;
    int idx = blockIdx.x * 256 + t;
    red[t] = (idx < NND) ? cnt[idx] : 0;
    __syncthreads();
    for (int off = 128; off > 0; off >>= 1) {
        if (t < off) red[t] += red[t + off];
        __syncthreads();
    }
    if (t == 0) bsum[blockIdx.x] = red[0];
}

__global__ __launch_bounds__(256) void k_bscan(int* __restrict__ bsum) {
    __shared__ int ps[256];
    int t = threadIdx.x;
    int v = (t < NSCB) ? bsum[t] : 0;
    ps[t] = v;
    __syncthreads();
    for (int off = 1; off < 256; off <<= 1) {
        int u = 0;
        if (t >= off) u = ps[t - off];
        __syncthreads();
        if (t >= off) ps[t] += u;
        __syncthreads();
    }
    if (t < NSCB) bsum[t] = ps[t] - v;   // exclusive
}

__global__ __launch_bounds__(256) void k_bout(const int* __restrict__ cnt,
                                              const int* __restrict__ bsum,
                                              int* __restrict__ rowstart) {
    __shared__ int ps[256];
    int t = threadIdx.x;
    int idx = blockIdx.x * 256 + t;
    int v = (idx < NND) ? cnt[idx] : 0;
    ps[t] = v;
    __syncthreads();
    for (int off = 1; off < 256; off <<= 1) {
        int u = 0;
        if (t >= off) u = ps[t - off];
        __syncthreads();
        if (t >= off) ps[t] += u;
        __syncthreads();
    }
    int boff = bsum[blockIdx.x];
    if (idx < NND) rowstart[idx] = boff + ps[t] - v;   // exclusive
    if (idx == NND - 1) rowstart[NND] = boff + ps[t];  // == NE
}

__global__ void k_fill(const int* __restrict__ ei, const int* __restrict__ rowstart,
                       int* __restrict__ cursor, int* __restrict__ adj) {
    int e = blockIdx.x * 256 + threadIdx.x;
    if (e >= NE) return;
    int s = ei[e], d = ei[NE + e];
    int pos = atomicAdd(&cursor[d], 1);
    adj[rowstart[d] + pos] = s;
}

// ---------------------------------------------------------------- cvt fp32 -> split bf16
__global__ void k_cvt(const float* __restrict__ in, unsigned short* __restrict__ hi,
                      unsigned short* __restrict__ lo, int n4) {
    int i = blockIdx.x * 256 + threadIdx.x;
    if (i >= n4) return;
    float4 v = ((const float4*)in)[i];
    ushort4 h, l;
    h.x = f2bf(v.x); l.x = f2bf(v.x - bf2f(h.x));
    h.y = f2bf(v.y); l.y = f2bf(v.y - bf2f(h.y));
    h.z = f2bf(v.z); l.z = f2bf(v.z - bf2f(h.z));
    h.w = f2bf(v.w); l.w = f2bf(v.w - bf2f(h.w));
    ((ushort4*)hi)[i] = h;
    ((ushort4*)lo)[i] = l;
}

// ---------------------------------------------------------------- MFMA GEMM
// C[M x Nc] = A[M x 128] @ B[128 x Nc] + bias, split-bf16 (3 MFMAs / tile).
// A given as hi/lo bf16 [M][128]; B given TRANSPOSED n-major hi/lo [Nc][128].
// 256 thr, tile 128x64, 4 waves: wave = (mw = w&1 -> 64 rows, nw = w>>1 -> 32 cols).
__global__ __launch_bounds__(256) void k_gemm_mfma(
    const unsigned short* __restrict__ Ahi, const unsigned short* __restrict__ Alo,
    const unsigned short* __restrict__ Bhi, const unsigned short* __restrict__ Blo,
    const float* __restrict__ bias, float* __restrict__ C,
    int M, int Nc)
{
    __shared__ unsigned short As_hi[128][72];
    __shared__ unsigned short As_lo[128][72];
    __shared__ unsigned short Bs_hi[64][72];
    __shared__ unsigned short Bs_lo[64][72];

    const int tid  = threadIdx.x;
    const int lane = tid & 63, wave = tid >> 6;
    const int mw = wave & 1, nw = wave >> 1;
    const int l15 = lane & 15, quad = lane >> 4;
    const int rowBase = blockIdx.x * 128;
    const int colBase = blockIdx.y * 64;

    f32x4 acc[4][2] = {};

    for (int kc = 0; kc < 128; kc += 64) {
        // stage A (128 rows x 64 k) and B (64 n-rows x 64 k), 16B copies
        int lr = tid >> 3;            // 0..31
        int ko = (tid & 7) * 8;       // 0..56
        #pragma unroll
        for (int i = 0; i < 4; ++i) {
            int row = lr + i * 32;
            int g = rowBase + row;
            uint4 vh = make_uint4(0, 0, 0, 0), vl = make_uint4(0, 0, 0, 0);
            if (g < M) {
                vh = *(const uint4*)&Ahi[(size_t)g * 128 + kc + ko];
                vl = *(const uint4*)&Alo[(size_t)g * 128 + kc + ko];
            }
            *(uint4*)&As_hi[row][ko] = vh;
            *(uint4*)&As_lo[row][ko] = vl;
        }
        #pragma unroll
        for (int i = 0; i < 2; ++i) {
            int row = lr + i * 32;        // n within tile (Nc is a multiple of 64)
            int g = colBase + row;
            uint4 vh = *(const uint4*)&Bhi[(size_t)g * 128 + kc + ko];
            uint4 vl = *(const uint4*)&Blo[(size_t)g * 128 + kc + ko];
            *(uint4*)&Bs_hi[row][ko] = vh;
            *(uint4*)&Bs_lo[row][ko] = vl;
        }
        __syncthreads();

        #pragma unroll
        for (int kq = 0; kq < 2; ++kq) {
            int kof = kq * 32 + quad * 8;
            s16x8 ah[4], al[4], bh[2], bl[2];
            #pragma unroll
            for (int ms = 0; ms < 4; ++ms) {
                int r = mw * 64 + ms * 16 + l15;
                ah[ms] = *(const s16x8*)&As_hi[r][kof];
                al[ms] = *(const s16x8*)&As_lo[r][kof];
            }
            #pragma unroll
            for (int ns = 0; ns < 2; ++ns) {
                int r = nw * 32 + ns * 16 + l15;
                bh[ns] = *(const s16x8*)&Bs_hi[r][kof];
                bl[ns] = *(const s16x8*)&Bs_lo[r][kof];
            }
            #pragma unroll
            for (int ms = 0; ms < 4; ++ms)
                #pragma unroll
                for (int ns = 0; ns < 2; ++ns)
                    acc[ms][ns] = __builtin_amdgcn_mfma_f32_16x16x32_bf16(ah[ms], bh[ns], acc[ms][ns], 0, 0, 0);
            #pragma unroll
            for (int ms = 0; ms < 4; ++ms)
                #pragma unroll
                for (int ns = 0; ns < 2; ++ns)
                    acc[ms][ns] = __builtin_amdgcn_mfma_f32_16x16x32_bf16(al[ms], bh[ns], acc[ms][ns], 0, 0, 0);
            #pragma unroll
            for (int ms = 0; ms < 4; ++ms)
                #pragma unroll
                for (int ns = 0; ns < 2; ++ns)
                    acc[ms][ns] = __builtin_amdgcn_mfma_f32_16x16x32_bf16(ah[ms], bl[ns], acc[ms][ns], 0, 0, 0);
        }
        __syncthreads();
    }

    // epilogue: C/D layout col=lane&15, row=quad*4+reg
    #pragma unroll
    for (int ns = 0; ns < 2; ++ns) {
        int col = colBase + nw * 32 + ns * 16 + l15;
        float bv = bias ? bias[col] : 0.f;
        #pragma unroll
        for (int ms = 0; ms < 4; ++ms) {
            int row0 = rowBase + mw * 64 + ms * 16 + quad * 4;
            #pragma unroll
            for (int r = 0; r < 4; ++r) {
                int row = row0 + r;
                if (row < M) C[(size_t)row * Nc + col] = acc[ms][ns][r] + bv;
            }
        }
    }
}

// ---------------------------------------------------------------- GCN gather
// One wave per node; lane owns 2 cols (float2). agg = dn*(sum_s h[s]*ds + h[n]*dn),
// fused bias + relu + split-bf16 output (feeds the next MFMA GEMM directly).
// NOTE: hi/lo output MUST NOT alias h (blocks read arbitrary h rows).
__global__ __launch_bounds__(256) void k_gather(
    const int* __restrict__ rowstart, const int* __restrict__ adj,
    const float* __restrict__ h, const float* __restrict__ dinv,
    const float* __restrict__ bias,
    unsigned short* __restrict__ hi, unsigned short* __restrict__ lo)
{
    const int n    = blockIdx.x * 4 + (threadIdx.x >> 6);   // grid exactly NND/4
    const int lane = threadIdx.x & 63;
    const int r0 = rowstart[n], r1 = rowstart[n + 1];
    const float dn = dinv[n];

    float2 hv = *(const float2*)&h[(size_t)n * 128 + 2 * lane];
    float2 acc;
    acc.x = hv.x * dn;
    acc.y = hv.y * dn;
    for (int i = r0; i < r1; ++i) {
        int s = adj[i];                 // wave-uniform broadcast
        float ds = dinv[s];
        float2 v = *(const float2*)&h[(size_t)s * 128 + 2 * lane];
        acc.x += v.x * ds;
        acc.y += v.y * ds;
    }
    float2 bb = *(const float2*)&bias[2 * lane];
    float vx = fmaxf(acc.x * dn + bb.x, 0.f);
    float vy = fmaxf(acc.y * dn + bb.y, 0.f);
    ushort2 ho, lo2;
    ho.x = f2bf(vx); lo2.x = f2bf(vx - bf2f(ho.x));
    ho.y = f2bf(vy); lo2.y = f2bf(vy - bf2f(ho.y));
    *(ushort2*)&hi[(size_t)n * 128 + 2 * lane] = ho;
    *(ushort2*)&lo[(size_t)n * 128 + 2 * lane] = lo2;
}

// ---------------------------------------------------------------- prep kernels
// GCN weight W [128(k)][128(n)] fp32 -> transposed n-major split-bf16 [n][k]
__global__ void k_prep_gcnw(const float* __restrict__ W,
                            unsigned short* __restrict__ hi, unsigned short* __restrict__ lo) {
    int t = blockIdx.x * 256 + threadIdx.x;
    if (t >= 16384) return;
    int k = t >> 7, n = t & 127;
    float v = W[t];
    unsigned short h = f2bf(v);
    hi[n * 128 + k] = h;
    lo[n * 128 + k] = f2bf(v - bf2f(h));
}

// LSTM prep: both w_ih and w_hh [512(r=g*128+j)][128(k)] -> packed-transposed
// split-bf16 wT[p=j*4+g][k]; bias -> bp[p] = b_ih + b_hh.
__global__ void k_prep_lstm(const float* __restrict__ w_ih, const float* __restrict__ w_hh,
                            const float* __restrict__ b_ih, const float* __restrict__ b_hh,
                            unsigned short* __restrict__ ih_hi, unsigned short* __restrict__ ih_lo,
                            unsigned short* __restrict__ hh_hi, unsigned short* __restrict__ hh_lo,
                            float* __restrict__ bp)
{
    int t = blockIdx.x * 256 + threadIdx.x;
    if (t < 65536) {
        int r = t >> 7, k = t & 127;
        int g = r >> 7, j = r & 127;
        int p = (j << 2) + g;
        float v = w_ih[t];
        unsigned short h = f2bf(v);
        ih_hi[p * 128 + k] = h;
        ih_lo[p * 128 + k] = f2bf(v - bf2f(h));
    } else if (t < 131072) {
        int t2 = t - 65536;
        int r = t2 >> 7, k = t2 & 127;
        int g = r >> 7, j = r & 127;
        int p = (j << 2) + g;
        float v = w_hh[t2];
        unsigned short h = f2bf(v);
        hh_hi[p * 128 + k] = h;
        hh_lo[p * 128 + k] = f2bf(v - bf2f(h));
    } else if (t < 131584) {
        int r = t - 131072;   // 0..511
        int g = r >> 7, j = r & 127;
        bp[(j << 2) + g] = b_ih[r] + b_hh[r];
    }
}

// ---------------------------------------------------------------- LSTM recurrence
// v8 = v7 + chunked G loads + deferred H stores (barrier-drain amortization).
// __syncthreads emits s_waitcnt vmcnt(0): any in-flight global op is drained
// at every barrier. So (a) G gate inputs are loaded CHK steps at a time into
// registers (one drain per chunk, not per step); (b) H outputs are buffered
// in registers and flushed once per chunk (drains amortize the same way).
__global__ __launch_bounds__(512, 2) void k_lstm(
    const float* __restrict__ G,            // (NB*TSEQ) x 512, gate-packed cols
    const unsigned short* __restrict__ Whi, // 512 x 128, packed-transposed hi
    const unsigned short* __restrict__ Wlo, // lo
    unsigned short* __restrict__ Hhi,       // (NB*TSEQ) x 128 bf16-hi, or nullptr
    unsigned short* __restrict__ Hlo,       // bf16-lo, or nullptr
    float* __restrict__ Hlast)              // NB x 128 fp32 (last step), or nullptr
{
    const int tid  = threadIdx.x;
    const int lane = tid & 63, wave = tid >> 6;   // 8 waves
    const int l15  = lane & 15, quad = lane >> 4;
    const int b0   = blockIdx.x * SB;

    __shared__ unsigned short Ah[16 * AHS];  // h hi (rows SB..15 stay zero)
    __shared__ unsigned short Al[16 * AHS];  // h lo
    __shared__ float part[16][516];          // P in C/D layout (row=m, col=n)

    // weight fragments: wave owns n-tiles nt0..nt0+3 (n = p = j*4+gate)
    const int nt0 = wave * 4;
    s16x8 bh[4][4], bl[4][4];   // [nt][ks]
    #pragma unroll
    for (int nt = 0; nt < 4; ++nt) {
        int p = (nt0 + nt) * 16 + l15;
        #pragma unroll
        for (int ks = 0; ks < 4; ++ks) {
            bh[nt][ks] = *(const s16x8*)&Whi[(size_t)p * 128 + ks * 32 + quad * 8];
            bl[nt][ks] = *(const s16x8*)&Wlo[(size_t)p * 128 + ks * 32 + quad * 8];
        }
    }

    for (int i = tid; i < 16 * AHS; i += 512) { Ah[i] = 0; Al[i] = 0; }

    const int j2 = tid & 127;      // phase-2 hidden unit
    const int b  = tid >> 7;       // phase-2 batch slot (0..3)
    const int bg = b0 + b;         // always < NB (NB % SB == 0)
    float c = 0.f;
    float hn_last = 0.f;
    __syncthreads();

    const float* gbase = &G[((size_t)bg * TSEQ) * 512 + (j2 << 2)];

    for (int cc = 0; cc < TSEQ / CHK; ++cc) {
        // batch-load this chunk's CHK gate inputs (all in flight together;
        // the chunk's first barrier pays one drain instead of CHK drains)
        float4 gchunk[CHK];
        #pragma unroll
        for (int s = 0; s < CHK; ++s)
            gchunk[s] = *(const float4*)&gbase[(size_t)(cc * CHK + s) * 512];

        unsigned int hbuf[CHK];

        #pragma unroll
        for (int s = 0; s < CHK; ++s) {
            // phase 1: MFMA  P = h @ W^T  (split bf16, lo*lo dropped)
            f32x4 acc[4] = {};
            #pragma unroll
            for (int ks = 0; ks < 4; ++ks) {
                s16x8 ah = *(const s16x8*)&Ah[l15 * AHS + ks * 32 + quad * 8];
                s16x8 al = *(const s16x8*)&Al[l15 * AHS + ks * 32 + quad * 8];
                #pragma unroll
                for (int nt = 0; nt < 4; ++nt) {
                    acc[nt] = __builtin_amdgcn_mfma_f32_16x16x32_bf16(ah, bh[nt][ks], acc[nt], 0, 0, 0);
                    acc[nt] = __builtin_amdgcn_mfma_f32_16x16x32_bf16(al, bh[nt][ks], acc[nt], 0, 0, 0);
                    acc[nt] = __builtin_amdgcn_mfma_f32_16x16x32_bf16(ah, bl[nt][ks], acc[nt], 0, 0, 0);
                }
            }
            // write P: row m=quad*4+r, col n=(nt0+nt)*16+l15
            #pragma unroll
            for (int nt = 0; nt < 4; ++nt)
                #pragma unroll
                for (int r = 0; r < 4; ++r)
                    part[quad * 4 + r][(nt0 + nt) * 16 + l15] = acc[nt][r];
            __syncthreads();

            // phase 2: LSTM cell for the (b, j2) pair
            {
                float4 pa = *(const float4*)&part[b][j2 << 2];
                float xi = pa.x + gchunk[s].x;
                float xf = pa.y + gchunk[s].y;
                float xg = pa.z + gchunk[s].z;
                float xo = pa.w + gchunk[s].w;
                float ii = sigf(xi), ff = sigf(xf), gg = tanhfast(xg), oo = sigf(xo);
                float cn = ff * c + ii * gg;
                c = cn;
                float hn = oo * tanhfast(cn);
                hn_last = hn;
                unsigned short hh = f2bf(hn);
                unsigned short hl = f2bf(hn - bf2f(hh));
                Ah[b * AHS + j2] = hh;
                Al[b * AHS + j2] = hl;
                hbuf[s] = ((unsigned int)hh << 16) | hl;
            }
            __syncthreads();
        }

        // flush the chunk's h outputs (drains once, at next chunk's barrier)
        if (Hhi) {
            #pragma unroll
            for (int s = 0; s < CHK; ++s) {
                int step = cc * CHK + s;
                Hhi[((size_t)bg * TSEQ + step) * 128 + j2] = (unsigned short)(hbuf[s] >> 16);
                Hlo[((size_t)bg * TSEQ + step) * 128 + j2] = (unsigned short)(hbuf[s] & 0xffffu);
            }
        }
    }

    if (Hlast)
        Hlast[(size_t)bg * 128 + j2] = hn_last;
}

// ---------------------------------------------------------------- FC head
// last: NB x 128 fp32 (compact last-step h)
__global__ __launch_bounds__(256) void k_fc(
    const float* __restrict__ last, const float* __restrict__ fcw,
    const float* __restrict__ fcb, float* __restrict__ out)
{
    int b    = blockIdx.x * 4 + (threadIdx.x >> 6);
    int lane = threadIdx.x & 63;
    const float* row = &last[(size_t)b * 128];
    float v = row[lane] * fcw[lane] + row[lane + 64] * fcw[lane + 64];
    #pragma unroll
    for (int off = 32; off > 0; off >>= 1)
        v += __shfl_down(v, off);
    if (lane == 0) out[b] = v + fcb[0];
}

// ---------------------------------------------------------------- launch
extern "C" void kernel_launch(void* const* d_in, const int* in_sizes, int n_in,
                              void* d_out, int out_size, void* d_ws, size_t ws_size,
                              hipStream_t stream)
{
    const float* x    = (const float*)d_in[0];
    const int*   ei   = (const int*)d_in[1];
    const float* W1   = (const float*)d_in[3];
    const float* b1   = (const float*)d_in[4];
    const float* W2   = (const float*)d_in[5];
    const float* b2   = (const float*)d_in[6];
    const float* fcw  = (const float*)d_in[7];
    const float* fcb  = (const float*)d_in[8];
    const float* wih0 = (const float*)d_in[9];
    const float* whh0 = (const float*)d_in[10];
    const float* bih0 = (const float*)d_in[11];
    const float* bhh0 = (const float*)d_in[12];
    const float* wih1 = (const float*)d_in[13];
    const float* whh1 = (const float*)d_in[14];
    const float* bih1 = (const float*)d_in[15];
    const float* bhh1 = (const float*)d_in[16];
    float* out = (float*)d_out;

    char* ws = (char*)d_ws;
    // ---- persistent regions
    unsigned short* shi = (unsigned short*)(ws + 0);          // 12.8 MB
    unsigned short* slo = (unsigned short*)(ws + 12800000);   // 12.8 MB (ends 25.6M)
    float* bufX = (float*)(ws + 25600000);                    // 0.512 MB (NB x 128; ends 26.2M)
    float* bufG = (float*)(ws + 51200000);                    // 102.4 MB (ends 153.6M)

    // ---- GCN-phase regions (inside bufG, dead before gate GEMM writes bufG)
    unsigned short* xhi = (unsigned short*)(ws + 51200000);   // 12.8 MB
    unsigned short* xlo = (unsigned short*)(ws + 64000000);   // 12.8 MB
    float* bufHg  = (float*)(ws + 76800000);                  // 25.6 MB (ends 102.4M)
    int* cnt      = (int*)(ws + 102400000);
    int* rowstart = (int*)(ws + 102604800);
    int* cursor   = (int*)(ws + 102809600);
    int* adj      = (int*)(ws + 103014400);                   // 2.4 MB (ends 105.42M)
    int* bsum     = (int*)(ws + 105420800);                   // NSCB ints

    float* dinv = (float*)(ws + 153600000);
    float* bp0  = (float*)(ws + 153800192);
    float* bp1  = (float*)(ws + 153802240);
    unsigned short* w1t_hi   = (unsigned short*)(ws + 153804288);
    unsigned short* w1t_lo   = (unsigned short*)(ws + 153837056);
    unsigned short* w2t_hi   = (unsigned short*)(ws + 153869824);
    unsigned short* w2t_lo   = (unsigned short*)(ws + 153902592);
    unsigned short* wpih0_hi = (unsigned short*)(ws + 153935360);
    unsigned short* wpih0_lo = (unsigned short*)(ws + 154066432);
    unsigned short* wpih1_hi = (unsigned short*)(ws + 154197504);
    unsigned short* wpih1_lo = (unsigned short*)(ws + 154328576);
    unsigned short* wphh0_hi = (unsigned short*)(ws + 154459648);
    unsigned short* wphh0_lo = (unsigned short*)(ws + 154590720);
    unsigned short* wphh1_hi = (unsigned short*)(ws + 154721792);
    unsigned short* wphh1_lo = (unsigned short*)(ws + 154852864);

    // ---- CSR build + dinv (multi-block scan)
    hipMemsetAsync(cnt, 0, NND * sizeof(int), stream);
    hipMemsetAsync(cursor, 0, NND * sizeof(int), stream);
    k_count<<<(NE + 255) / 256, 256, 0, stream>>>(ei, cnt);
    k_bsum<<<NSCB, 256, 0, stream>>>(cnt, bsum);
    k_bscan<<<1, 256, 0, stream>>>(bsum);
    k_bout<<<NSCB, 256, 0, stream>>>(cnt, bsum, rowstart);
    k_dinv<<<(NND + 255) / 256, 256, 0, stream>>>(cnt, dinv);
    k_fill<<<(NE + 255) / 256, 256, 0, stream>>>(ei, rowstart, cursor, adj);

    // ---- weight prep
    k_prep_gcnw<<<64, 256, 0, stream>>>(W1, w1t_hi, w1t_lo);
    k_prep_gcnw<<<64, 256, 0, stream>>>(W2, w2t_hi, w2t_lo);
    k_prep_lstm<<<514, 256, 0, stream>>>(wih0, whh0, bih0, bhh0,
                                         wpih0_hi, wpih0_lo, wphh0_hi, wphh0_lo, bp0);
    k_prep_lstm<<<514, 256, 0, stream>>>(wih1, whh1, bih1, bhh1,
                                         wpih1_hi, wpih1_lo, wphh1_hi, wphh1_lo, bp1);

    dim3 gH(391, 2);   // 128-col GEMMs (ceil(50000/128)=391)
    dim3 gG(391, 8);   // 512-col GEMMs

    // ---- GCN layer 1
    k_cvt<<<6250, 256, 0, stream>>>(x, xhi, xlo, NND * 128 / 4);
    k_gemm_mfma<<<gH, 256, 0, stream>>>(xhi, xlo, w1t_hi, w1t_lo, nullptr, bufHg, NND, 128);
    k_gather<<<NND / 4, 256, 0, stream>>>(rowstart, adj, bufHg, dinv, b1, xhi, xlo);

    // ---- GCN layer 2 (gather writes shi/slo @0-25.6M, disjoint from bufHg)
    k_gemm_mfma<<<gH, 256, 0, stream>>>(xhi, xlo, w2t_hi, w2t_lo, nullptr, bufHg, NND, 128);
    k_gather<<<NND / 4, 256, 0, stream>>>(rowstart, adj, bufHg, dinv, b2, shi, slo);

    // ---- LSTM layer 0: gate GEMM + MFMA recurrence (emits split-bf16 seq0 -> shi/slo)
    k_gemm_mfma<<<gG, 256, 0, stream>>>(shi, slo, wpih0_hi, wpih0_lo, bp0, bufG, NND, 512);
    k_lstm<<<NB / SB, 512, 0, stream>>>(bufG, wphh0_hi, wphh0_lo, shi, slo, nullptr);

    // ---- LSTM layer 1 (reads gates; emits only compact last-step fp32 -> bufX)
    k_gemm_mfma<<<gG, 256, 0, stream>>>(shi, slo, wpih1_hi, wpih1_lo, bp1, bufG, NND, 512);
    k_lstm<<<NB / SB, 512, 0, stream>>>(bufG, wphh1_hi, wphh1_lo, nullptr, nullptr, bufX);

    // ---- FC head
    k_fc<<<NB / 4, 256, 0, stream>>>(bufX, fcw, fcb, out);
}

// Round 14
// 658.725 us; speedup vs baseline: 1.0273x; 1.0273x over previous
//
#include <hip/hip_runtime.h>

// Problem constants (fixed by the reference file)
#define NND 50000   // nodes
#define NE  600000  // edges
#define TSEQ 50     // sequence length
#define NB  1000    // batch = NND/TSEQ
#define SB  4       // sequences per LSTM workgroup (250 WGs ~= 1/CU)
                    // NOTE: M=16 MFMA tile => per-WG cost invariant in SB.
                    // SB=16: 63 WGs (141us), SB=4: 250 WGs (88.6us), SB=2:
                    // 500 WGs = 2x total MFMA work (147.6us, R11 regression).
#define AHS 136     // LDS h-row stride in shorts (128 + 8 pad, 16B-aligned)
#define NSCB 196    // scan blocks: ceil(NND/256)

typedef __attribute__((ext_vector_type(4))) float f32x4;
typedef __attribute__((ext_vector_type(8))) short s16x8;

// ---------------------------------------------------------------- helpers
__device__ __forceinline__ float sigf(float x) {
    return 1.0f / (1.0f + __expf(-x));
}
__device__ __forceinline__ float tanhfast(float x) {
    x = fminf(fmaxf(x, -15.f), 15.f);
    float e = __expf(2.f * x);
    return (e - 1.f) / (e + 1.f);
}
// bf16 bit helpers (round-to-nearest-even)
__device__ __forceinline__ unsigned short f2bf(float f) {
    unsigned int u = __float_as_uint(f);
    u = u + 0x7FFFu + ((u >> 16) & 1u);
    return (unsigned short)(u >> 16);
}
__device__ __forceinline__ float bf2f(unsigned short h) {
    return __uint_as_float(((unsigned int)h) << 16);
}

// ---------------------------------------------------------------- CSR build
__global__ void k_count(const int* __restrict__ ei, int* __restrict__ cnt) {
    int e = blockIdx.x * 256 + threadIdx.x;
    if (e < NE) atomicAdd(&cnt[ei[NE + e]], 1);
}

__global__ void k_dinv(const int* __restrict__ cnt, float* __restrict__ dinv) {
    int i = blockIdx.x * 256 + threadIdx.x;
    if (i < NND) dinv[i] = 1.0f / sqrtf((float)cnt[i] + 1.0f);
}

// ---- 3-stage multi-block exclusive scan of cnt -> rowstart
__global__ __launch_bounds__(256) void k_bsum(const int* __restrict__ cnt,
                                              int* __restrict__ bsum) {
    __shared__ int red[256];
    int t = threadIdx.x;
    int idx = blockIdx.x * 256 + t;
    red[t] = (idx < NND) ? cnt[idx] : 0;
    __syncthreads();
    for (int off = 128; off > 0; off >>= 1) {
        if (t < off) red[t] += red[t + off];
        __syncthreads();
    }
    if (t == 0) bsum[blockIdx.x] = red[0];
}

__global__ __launch_bounds__(256) void k_bscan(int* __restrict__ bsum) {
    __shared__ int ps[256];
    int t = threadIdx.x;
    int v = (t < NSCB) ? bsum[t] : 0;
    ps[t] = v;
    __syncthreads();
    for (int off = 1; off < 256; off <<= 1) {
        int u = 0;
        if (t >= off) u = ps[t - off];
        __syncthreads();
        if (t >= off) ps[t] += u;
        __syncthreads();
    }
    if (t < NSCB) bsum[t] = ps[t] - v;   // exclusive
}

__global__ __launch_bounds__(256) void k_bout(const int* __restrict__ cnt,
                                              const int* __restrict__ bsum,
                                              int* __restrict__ rowstart) {
    __shared__ int ps[256];
    int t = threadIdx.x;
    int idx = blockIdx.x * 256 + t;
    int v = (idx < NND) ? cnt[idx] : 0;
    ps[t] = v;
    __syncthreads();
    for (int off = 1; off < 256; off <<= 1) {
        int u = 0;
        if (t >= off) u = ps[t - off];
        __syncthreads();
        if (t >= off) ps[t] += u;
        __syncthreads();
    }
    int boff = bsum[blockIdx.x];
    if (idx < NND) rowstart[idx] = boff + ps[t] - v;   // exclusive
    if (idx == NND - 1) rowstart[NND] = boff + ps[t];  // == NE
}

__global__ void k_fill(const int* __restrict__ ei, const int* __restrict__ rowstart,
                       int* __restrict__ cursor, int* __restrict__ adj) {
    int e = blockIdx.x * 256 + threadIdx.x;
    if (e >= NE) return;
    int s = ei[e], d = ei[NE + e];
    int pos = atomicAdd(&cursor[d], 1);
    adj[rowstart[d] + pos] = s;
}

// ---------------------------------------------------------------- cvt fp32 -> split bf16
__global__ void k_cvt(const float* __restrict__ in, unsigned short* __restrict__ hi,
                      unsigned short* __restrict__ lo, int n4) {
    int i = blockIdx.x * 256 + threadIdx.x;
    if (i >= n4) return;
    float4 v = ((const float4*)in)[i];
    ushort4 h, l;
    h.x = f2bf(v.x); l.x = f2bf(v.x - bf2f(h.x));
    h.y = f2bf(v.y); l.y = f2bf(v.y - bf2f(h.y));
    h.z = f2bf(v.z); l.z = f2bf(v.z - bf2f(h.z));
    h.w = f2bf(v.w); l.w = f2bf(v.w - bf2f(h.w));
    ((ushort4*)hi)[i] = h;
    ((ushort4*)lo)[i] = l;
}

// ---------------------------------------------------------------- MFMA GEMM
// C[M x Nc] = A[M x 128] @ B[128 x Nc] + bias, split-bf16 (3 MFMAs / tile).
// A given as hi/lo bf16 [M][128]; B given TRANSPOSED n-major hi/lo [Nc][128].
// 256 thr, tile 128x64, 4 waves: wave = (mw = w&1 -> 64 rows, nw = w>>1 -> 32 cols).
__global__ __launch_bounds__(256) void k_gemm_mfma(
    const unsigned short* __restrict__ Ahi, const unsigned short* __restrict__ Alo,
    const unsigned short* __restrict__ Bhi, const unsigned short* __restrict__ Blo,
    const float* __restrict__ bias, float* __restrict__ C,
    int M, int Nc)
{
    __shared__ unsigned short As_hi[128][72];
    __shared__ unsigned short As_lo[128][72];
    __shared__ unsigned short Bs_hi[64][72];
    __shared__ unsigned short Bs_lo[64][72];

    const int tid  = threadIdx.x;
    const int lane = tid & 63, wave = tid >> 6;
    const int mw = wave & 1, nw = wave >> 1;
    const int l15 = lane & 15, quad = lane >> 4;
    const int rowBase = blockIdx.x * 128;
    const int colBase = blockIdx.y * 64;

    f32x4 acc[4][2] = {};

    for (int kc = 0; kc < 128; kc += 64) {
        // stage A (128 rows x 64 k) and B (64 n-rows x 64 k), 16B copies
        int lr = tid >> 3;            // 0..31
        int ko = (tid & 7) * 8;       // 0..56
        #pragma unroll
        for (int i = 0; i < 4; ++i) {
            int row = lr + i * 32;
            int g = rowBase + row;
            uint4 vh = make_uint4(0, 0, 0, 0), vl = make_uint4(0, 0, 0, 0);
            if (g < M) {
                vh = *(const uint4*)&Ahi[(size_t)g * 128 + kc + ko];
                vl = *(const uint4*)&Alo[(size_t)g * 128 + kc + ko];
            }
            *(uint4*)&As_hi[row][ko] = vh;
            *(uint4*)&As_lo[row][ko] = vl;
        }
        #pragma unroll
        for (int i = 0; i < 2; ++i) {
            int row = lr + i * 32;        // n within tile (Nc is a multiple of 64)
            int g = colBase + row;
            uint4 vh = *(const uint4*)&Bhi[(size_t)g * 128 + kc + ko];
            uint4 vl = *(const uint4*)&Blo[(size_t)g * 128 + kc + ko];
            *(uint4*)&Bs_hi[row][ko] = vh;
            *(uint4*)&Bs_lo[row][ko] = vl;
        }
        __syncthreads();

        #pragma unroll
        for (int kq = 0; kq < 2; ++kq) {
            int kof = kq * 32 + quad * 8;
            s16x8 ah[4], al[4], bh[2], bl[2];
            #pragma unroll
            for (int ms = 0; ms < 4; ++ms) {
                int r = mw * 64 + ms * 16 + l15;
                ah[ms] = *(const s16x8*)&As_hi[r][kof];
                al[ms] = *(const s16x8*)&As_lo[r][kof];
            }
            #pragma unroll
            for (int ns = 0; ns < 2; ++ns) {
                int r = nw * 32 + ns * 16 + l15;
                bh[ns] = *(const s16x8*)&Bs_hi[r][kof];
                bl[ns] = *(const s16x8*)&Bs_lo[r][kof];
            }
            #pragma unroll
            for (int ms = 0; ms < 4; ++ms)
                #pragma unroll
                for (int ns = 0; ns < 2; ++ns)
                    acc[ms][ns] = __builtin_amdgcn_mfma_f32_16x16x32_bf16(ah[ms], bh[ns], acc[ms][ns], 0, 0, 0);
            #pragma unroll
            for (int ms = 0; ms < 4; ++ms)
                #pragma unroll
                for (int ns = 0; ns < 2; ++ns)
                    acc[ms][ns] = __builtin_amdgcn_mfma_f32_16x16x32_bf16(al[ms], bh[ns], acc[ms][ns], 0, 0, 0);
            #pragma unroll
            for (int ms = 0; ms < 4; ++ms)
                #pragma unroll
                for (int ns = 0; ns < 2; ++ns)
                    acc[ms][ns] = __builtin_amdgcn_mfma_f32_16x16x32_bf16(ah[ms], bl[ns], acc[ms][ns], 0, 0, 0);
        }
        __syncthreads();
    }

    // epilogue: C/D layout col=lane&15, row=quad*4+reg
    #pragma unroll
    for (int ns = 0; ns < 2; ++ns) {
        int col = colBase + nw * 32 + ns * 16 + l15;
        float bv = bias ? bias[col] : 0.f;
        #pragma unroll
        for (int ms = 0; ms < 4; ++ms) {
            int row0 = rowBase + mw * 64 + ms * 16 + quad * 4;
            #pragma unroll
            for (int r = 0; r < 4; ++r) {
                int row = row0 + r;
                if (row < M) C[(size_t)row * Nc + col] = acc[ms][ns][r] + bv;
            }
        }
    }
}

// ---------------------------------------------------------------- GCN gather
// One wave per node; lane owns 2 cols (float2). agg = dn*(sum_s h[s]*ds + h[n]*dn),
// fused bias + relu + split-bf16 output (feeds the next MFMA GEMM directly).
// NOTE: hi/lo output MUST NOT alias h (blocks read arbitrary h rows).
__global__ __launch_bounds__(256) void k_gather(
    const int* __restrict__ rowstart, const int* __restrict__ adj,
    const float* __restrict__ h, const float* __restrict__ dinv,
    const float* __restrict__ bias,
    unsigned short* __restrict__ hi, unsigned short* __restrict__ lo)
{
    const int n    = blockIdx.x * 4 + (threadIdx.x >> 6);   // grid exactly NND/4
    const int lane = threadIdx.x & 63;
    const int r0 = rowstart[n], r1 = rowstart[n + 1];
    const float dn = dinv[n];

    float2 hv = *(const float2*)&h[(size_t)n * 128 + 2 * lane];
    float2 acc;
    acc.x = hv.x * dn;
    acc.y = hv.y * dn;
    for (int i = r0; i < r1; ++i) {
        int s = adj[i];                 // wave-uniform broadcast
        float ds = dinv[s];
        float2 v = *(const float2*)&h[(size_t)s * 128 + 2 * lane];
        acc.x += v.x * ds;
        acc.y += v.y * ds;
    }
    float2 bb = *(const float2*)&bias[2 * lane];
    float vx = fmaxf(acc.x * dn + bb.x, 0.f);
    float vy = fmaxf(acc.y * dn + bb.y, 0.f);
    ushort2 ho, lo2;
    ho.x = f2bf(vx); lo2.x = f2bf(vx - bf2f(ho.x));
    ho.y = f2bf(vy); lo2.y = f2bf(vy - bf2f(ho.y));
    *(ushort2*)&hi[(size_t)n * 128 + 2 * lane] = ho;
    *(ushort2*)&lo[(size_t)n * 128 + 2 * lane] = lo2;
}

// ---------------------------------------------------------------- prep kernels
// GCN weight W [128(k)][128(n)] fp32 -> transposed n-major split-bf16 [n][k]
__global__ void k_prep_gcnw(const float* __restrict__ W,
                            unsigned short* __restrict__ hi, unsigned short* __restrict__ lo) {
    int t = blockIdx.x * 256 + threadIdx.x;
    if (t >= 16384) return;
    int k = t >> 7, n = t & 127;
    float v = W[t];
    unsigned short h = f2bf(v);
    hi[n * 128 + k] = h;
    lo[n * 128 + k] = f2bf(v - bf2f(h));
}

// LSTM prep: both w_ih and w_hh [512(r=g*128+j)][128(k)] -> packed-transposed
// split-bf16 wT[p=j*4+g][k]; bias -> bp[p] = b_ih + b_hh.
__global__ void k_prep_lstm(const float* __restrict__ w_ih, const float* __restrict__ w_hh,
                            const float* __restrict__ b_ih, const float* __restrict__ b_hh,
                            unsigned short* __restrict__ ih_hi, unsigned short* __restrict__ ih_lo,
                            unsigned short* __restrict__ hh_hi, unsigned short* __restrict__ hh_lo,
                            float* __restrict__ bp)
{
    int t = blockIdx.x * 256 + threadIdx.x;
    if (t < 65536) {
        int r = t >> 7, k = t & 127;
        int g = r >> 7, j = r & 127;
        int p = (j << 2) + g;
        float v = w_ih[t];
        unsigned short h = f2bf(v);
        ih_hi[p * 128 + k] = h;
        ih_lo[p * 128 + k] = f2bf(v - bf2f(h));
    } else if (t < 131072) {
        int t2 = t - 65536;
        int r = t2 >> 7, k = t2 & 127;
        int g = r >> 7, j = r & 127;
        int p = (j << 2) + g;
        float v = w_hh[t2];
        unsigned short h = f2bf(v);
        hh_hi[p * 128 + k] = h;
        hh_lo[p * 128 + k] = f2bf(v - bf2f(h));
    } else if (t < 131584) {
        int r = t - 131072;   // 0..511
        int g = r >> 7, j = r & 127;
        bp[(j << 2) + g] = b_ih[r] + b_hh[r];
    }
}

// ---------------------------------------------------------------- LSTM recurrence
// v9: ONE barrier per step via intra-wave phase-2.
// Wave w owns gate-cols [64w, 64w+64). Its quad-0 lanes hold ALL used P rows
// (rows 0..3 = the 4 sequences). Phase-2 is remapped so lane l of wave w
// handles (b = l>>4, j = 16w + (l&15)) -- fed ONLY by wave w's accumulators
// through a per-wave LDS patch (intra-wave exchange: lgkmcnt, no barrier).
// The only cross-wave data is Ah/Al (next step's A operand) -> 1 barrier/step.
__global__ __launch_bounds__(512, 2) void k_lstm(
    const float* __restrict__ G,            // (NB*TSEQ) x 512, gate-packed cols
    const unsigned short* __restrict__ Whi, // 512 x 128, packed-transposed hi
    const unsigned short* __restrict__ Wlo, // lo
    unsigned short* __restrict__ Hhi,       // (NB*TSEQ) x 128 bf16-hi, or nullptr
    unsigned short* __restrict__ Hlo,       // bf16-lo, or nullptr
    float* __restrict__ Hlast)              // NB x 128 fp32 (last step), or nullptr
{
    const int tid  = threadIdx.x;
    const int lane = tid & 63, wave = tid >> 6;   // 8 waves
    const int l15  = lane & 15, quad = lane >> 4;
    const int b0   = blockIdx.x * SB;

    __shared__ unsigned short Ah[16 * AHS];  // h hi (rows SB..15 stay zero)
    __shared__ unsigned short Al[16 * AHS];  // h lo
    __shared__ float partw[8][4][72];        // per-wave P patch [wave][b][col in wave]

    // weight fragments: wave owns n-tiles nt0..nt0+3 (n = p = j*4+gate)
    const int nt0 = wave * 4;
    s16x8 bh[4][4], bl[4][4];   // [nt][ks]
    #pragma unroll
    for (int nt = 0; nt < 4; ++nt) {
        int p = (nt0 + nt) * 16 + l15;
        #pragma unroll
        for (int ks = 0; ks < 4; ++ks) {
            bh[nt][ks] = *(const s16x8*)&Whi[(size_t)p * 128 + ks * 32 + quad * 8];
            bl[nt][ks] = *(const s16x8*)&Wlo[(size_t)p * 128 + ks * 32 + quad * 8];
        }
    }

    for (int i = tid; i < 16 * AHS; i += 512) { Ah[i] = 0; Al[i] = 0; }

    // phase-2 mapping: lane l of wave w -> (b2, j) with j owned by wave w
    const int b2 = lane >> 4;              // 0..3
    const int jj = wave * 16 + l15;        // hidden unit this lane updates
    const int bg = b0 + b2;                // sequence index (NB % SB == 0)
    float c = 0.f;
    float hn_last = 0.f;
    __syncthreads();

    const float* gbase = &G[((size_t)bg * TSEQ) * 512 + (jj << 2)];

    for (int step = 0; step < TSEQ; ++step) {
        // gate input for phase 2 (issued early; covered by phase-1 MFMA time,
        // no intervening barrier to force-drain it)
        const float4 gv = *(const float4*)&gbase[(size_t)step * 512];

        // phase 1: MFMA  P = h @ W^T  (split bf16, lo*lo dropped)
        f32x4 acc[4] = {};
        #pragma unroll
        for (int ks = 0; ks < 4; ++ks) {
            s16x8 ah = *(const s16x8*)&Ah[l15 * AHS + ks * 32 + quad * 8];
            s16x8 al = *(const s16x8*)&Al[l15 * AHS + ks * 32 + quad * 8];
            #pragma unroll
            for (int nt = 0; nt < 4; ++nt) {
                acc[nt] = __builtin_amdgcn_mfma_f32_16x16x32_bf16(ah, bh[nt][ks], acc[nt], 0, 0, 0);
                acc[nt] = __builtin_amdgcn_mfma_f32_16x16x32_bf16(al, bh[nt][ks], acc[nt], 0, 0, 0);
                acc[nt] = __builtin_amdgcn_mfma_f32_16x16x32_bf16(ah, bl[nt][ks], acc[nt], 0, 0, 0);
            }
        }

        // intra-wave exchange: quad-0 lanes hold rows 0..3 (the real seqs)
        if (quad == 0) {
            #pragma unroll
            for (int nt = 0; nt < 4; ++nt)
                #pragma unroll
                for (int r = 0; r < 4; ++r)
                    partw[wave][r][nt * 16 + l15] = acc[nt][r];
        }
        // same-wave producer/consumer: compiler inserts lgkmcnt wait, no barrier

        // phase 2: LSTM cell for (b2, jj); reads this wave's own patch
        {
            float4 pa = *(const float4*)&partw[wave][b2][l15 * 4];
            float xi = pa.x + gv.x;
            float xf = pa.y + gv.y;
            float xg = pa.z + gv.z;
            float xo = pa.w + gv.w;
            float ii = sigf(xi), ff = sigf(xf), gg = tanhfast(xg), oo = sigf(xo);
            float cn = ff * c + ii * gg;
            c = cn;
            float hn = oo * tanhfast(cn);
            hn_last = hn;
            unsigned short hh = f2bf(hn);
            unsigned short hl = f2bf(hn - bf2f(hh));
            Ah[b2 * AHS + jj] = hh;
            Al[b2 * AHS + jj] = hl;
            if (Hhi) {
                Hhi[((size_t)bg * TSEQ + step) * 128 + jj] = hh;
                Hlo[((size_t)bg * TSEQ + step) * 128 + jj] = hl;
            }
        }
        // single barrier: Ah/Al writes must be visible to all waves' phase-1
        __syncthreads();
    }

    if (Hlast)
        Hlast[(size_t)bg * 128 + jj] = hn_last;
}

// ---------------------------------------------------------------- FC head
// last: NB x 128 fp32 (compact last-step h)
__global__ __launch_bounds__(256) void k_fc(
    const float* __restrict__ last, const float* __restrict__ fcw,
    const float* __restrict__ fcb, float* __restrict__ out)
{
    int b    = blockIdx.x * 4 + (threadIdx.x >> 6);
    int lane = threadIdx.x & 63;
    const float* row = &last[(size_t)b * 128];
    float v = row[lane] * fcw[lane] + row[lane + 64] * fcw[lane + 64];
    #pragma unroll
    for (int off = 32; off > 0; off >>= 1)
        v += __shfl_down(v, off);
    if (lane == 0) out[b] = v + fcb[0];
}

// ---------------------------------------------------------------- launch
extern "C" void kernel_launch(void* const* d_in, const int* in_sizes, int n_in,
                              void* d_out, int out_size, void* d_ws, size_t ws_size,
                              hipStream_t stream)
{
    const float* x    = (const float*)d_in[0];
    const int*   ei   = (const int*)d_in[1];
    const float* W1   = (const float*)d_in[3];
    const float* b1   = (const float*)d_in[4];
    const float* W2   = (const float*)d_in[5];
    const float* b2   = (const float*)d_in[6];
    const float* fcw  = (const float*)d_in[7];
    const float* fcb  = (const float*)d_in[8];
    const float* wih0 = (const float*)d_in[9];
    const float* whh0 = (const float*)d_in[10];
    const float* bih0 = (const float*)d_in[11];
    const float* bhh0 = (const float*)d_in[12];
    const float* wih1 = (const float*)d_in[13];
    const float* whh1 = (const float*)d_in[14];
    const float* bih1 = (const float*)d_in[15];
    const float* bhh1 = (const float*)d_in[16];
    float* out = (float*)d_out;

    char* ws = (char*)d_ws;
    // ---- persistent regions
    unsigned short* shi = (unsigned short*)(ws + 0);          // 12.8 MB
    unsigned short* slo = (unsigned short*)(ws + 12800000);   // 12.8 MB (ends 25.6M)
    float* bufX = (float*)(ws + 25600000);                    // 0.512 MB (NB x 128; ends 26.2M)
    float* bufG = (float*)(ws + 51200000);                    // 102.4 MB (ends 153.6M)

    // ---- GCN-phase regions (inside bufG, dead before gate GEMM writes bufG)
    unsigned short* xhi = (unsigned short*)(ws + 51200000);   // 12.8 MB
    unsigned short* xlo = (unsigned short*)(ws + 64000000);   // 12.8 MB
    float* bufHg  = (float*)(ws + 76800000);                  // 25.6 MB (ends 102.4M)
    int* cnt      = (int*)(ws + 102400000);
    int* rowstart = (int*)(ws + 102604800);
    int* cursor   = (int*)(ws + 102809600);
    int* adj      = (int*)(ws + 103014400);                   // 2.4 MB (ends 105.42M)
    int* bsum     = (int*)(ws + 105420800);                   // NSCB ints

    float* dinv = (float*)(ws + 153600000);
    float* bp0  = (float*)(ws + 153800192);
    float* bp1  = (float*)(ws + 153802240);
    unsigned short* w1t_hi   = (unsigned short*)(ws + 153804288);
    unsigned short* w1t_lo   = (unsigned short*)(ws + 153837056);
    unsigned short* w2t_hi   = (unsigned short*)(ws + 153869824);
    unsigned short* w2t_lo   = (unsigned short*)(ws + 153902592);
    unsigned short* wpih0_hi = (unsigned short*)(ws + 153935360);
    unsigned short* wpih0_lo = (unsigned short*)(ws + 154066432);
    unsigned short* wpih1_hi = (unsigned short*)(ws + 154197504);
    unsigned short* wpih1_lo = (unsigned short*)(ws + 154328576);
    unsigned short* wphh0_hi = (unsigned short*)(ws + 154459648);
    unsigned short* wphh0_lo = (unsigned short*)(ws + 154590720);
    unsigned short* wphh1_hi = (unsigned short*)(ws + 154721792);
    unsigned short* wphh1_lo = (unsigned short*)(ws + 154852864);

    // ---- CSR build + dinv (multi-block scan)
    hipMemsetAsync(cnt, 0, NND * sizeof(int), stream);
    hipMemsetAsync(cursor, 0, NND * sizeof(int), stream);
    k_count<<<(NE + 255) / 256, 256, 0, stream>>>(ei, cnt);
    k_bsum<<<NSCB, 256, 0, stream>>>(cnt, bsum);
    k_bscan<<<1, 256, 0, stream>>>(bsum);
    k_bout<<<NSCB, 256, 0, stream>>>(cnt, bsum, rowstart);
    k_dinv<<<(NND + 255) / 256, 256, 0, stream>>>(cnt, dinv);
    k_fill<<<(NE + 255) / 256, 256, 0, stream>>>(ei, rowstart, cursor, adj);

    // ---- weight prep
    k_prep_gcnw<<<64, 256, 0, stream>>>(W1, w1t_hi, w1t_lo);
    k_prep_gcnw<<<64, 256, 0, stream>>>(W2, w2t_hi, w2t_lo);
    k_prep_lstm<<<514, 256, 0, stream>>>(wih0, whh0, bih0, bhh0,
                                         wpih0_hi, wpih0_lo, wphh0_hi, wphh0_lo, bp0);
    k_prep_lstm<<<514, 256, 0, stream>>>(wih1, whh1, bih1, bhh1,
                                         wpih1_hi, wpih1_lo, wphh1_hi, wphh1_lo, bp1);

    dim3 gH(391, 2);   // 128-col GEMMs (ceil(50000/128)=391)
    dim3 gG(391, 8);   // 512-col GEMMs

    // ---- GCN layer 1
    k_cvt<<<6250, 256, 0, stream>>>(x, xhi, xlo, NND * 128 / 4);
    k_gemm_mfma<<<gH, 256, 0, stream>>>(xhi, xlo, w1t_hi, w1t_lo, nullptr, bufHg, NND, 128);
    k_gather<<<NND / 4, 256, 0, stream>>>(rowstart, adj, bufHg, dinv, b1, xhi, xlo);

    // ---- GCN layer 2 (gather writes shi/slo @0-25.6M, disjoint from bufHg)
    k_gemm_mfma<<<gH, 256, 0, stream>>>(xhi, xlo, w2t_hi, w2t_lo, nullptr, bufHg, NND, 128);
    k_gather<<<NND / 4, 256, 0, stream>>>(rowstart, adj, bufHg, dinv, b2, shi, slo);

    // ---- LSTM layer 0: gate GEMM + MFMA recurrence (emits split-bf16 seq0 -> shi/slo)
    k_gemm_mfma<<<gG, 256, 0, stream>>>(shi, slo, wpih0_hi, wpih0_lo, bp0, bufG, NND, 512);
    k_lstm<<<NB / SB, 512, 0, stream>>>(bufG, wphh0_hi, wphh0_lo, shi, slo, nullptr);

    // ---- LSTM layer 1 (reads gates; emits only compact last-step fp32 -> bufX)
    k_gemm_mfma<<<gG, 256, 0, stream>>>(shi, slo, wpih1_hi, wpih1_lo, bp1, bufG, NND, 512);
    k_lstm<<<NB / SB, 512, 0, stream>>>(bufG, wphh1_hi, wphh1_lo, nullptr, nullptr, bufX);

    // ---- FC head
    k_fc<<<NB / 4, 256, 0, stream>>>(bufX, fcw, fcb, out);
}

// Round 15
// 644.759 us; speedup vs baseline: 1.0496x; 1.0217x over previous
//
#include <hip/hip_runtime.h>

// Problem constants (fixed by the reference file)
#define NND 50000   // nodes
#define NE  600000  // edges
#define TSEQ 50     // sequence length
#define NB  1000    // batch = NND/TSEQ
#define SB  4       // sequences per LSTM workgroup (250 WGs ~= 1/CU)
                    // M=16 MFMA tile => per-WG cost invariant in SB.
                    // SB=16: 63 WGs (141us), SB=4: 250 WGs (82us), SB=2:
                    // 500 WGs = 2x total MFMA work (147.6us, R11 regression).
#define AHS 136     // LDS h-row stride in shorts (128 + 8 pad, 16B-aligned)
#define NSCB 196    // scan blocks: ceil(NND/256)

typedef __attribute__((ext_vector_type(4))) float f32x4;
typedef __attribute__((ext_vector_type(8))) short s16x8;

// ---------------------------------------------------------------- helpers
__device__ __forceinline__ float sigf(float x) {
    return 1.0f / (1.0f + __expf(-x));
}
__device__ __forceinline__ float tanhfast(float x) {
    x = fminf(fmaxf(x, -15.f), 15.f);
    float e = __expf(2.f * x);
    return (e - 1.f) / (e + 1.f);
}
// bf16 bit helpers (round-to-nearest-even)
__device__ __forceinline__ unsigned short f2bf(float f) {
    unsigned int u = __float_as_uint(f);
    u = u + 0x7FFFu + ((u >> 16) & 1u);
    return (unsigned short)(u >> 16);
}
__device__ __forceinline__ float bf2f(unsigned short h) {
    return __uint_as_float(((unsigned int)h) << 16);
}

// ---------------------------------------------------------------- CSR build
__global__ void k_count(const int* __restrict__ ei, int* __restrict__ cnt) {
    int e = blockIdx.x * 256 + threadIdx.x;
    if (e < NE) atomicAdd(&cnt[ei[NE + e]], 1);
}

__global__ void k_dinv(const int* __restrict__ cnt, float* __restrict__ dinv) {
    int i = blockIdx.x * 256 + threadIdx.x;
    if (i < NND) dinv[i] = 1.0f / sqrtf((float)cnt[i] + 1.0f);
}

// ---- 3-stage multi-block exclusive scan of cnt -> rowstart
__global__ __launch_bounds__(256) void k_bsum(const int* __restrict__ cnt,
                                              int* __restrict__ bsum) {
    __shared__ int red[256];
    int t = threadIdx.x;
    int idx = blockIdx.x * 256 + t;
    red[t] = (idx < NND) ? cnt[idx] : 0;
    __syncthreads();
    for (int off = 128; off > 0; off >>= 1) {
        if (t < off) red[t] += red[t + off];
        __syncthreads();
    }
    if (t == 0) bsum[blockIdx.x] = red[0];
}

__global__ __launch_bounds__(256) void k_bscan(int* __restrict__ bsum) {
    __shared__ int ps[256];
    int t = threadIdx.x;
    int v = (t < NSCB) ? bsum[t] : 0;
    ps[t] = v;
    __syncthreads();
    for (int off = 1; off < 256; off <<= 1) {
        int u = 0;
        if (t >= off) u = ps[t - off];
        __syncthreads();
        if (t >= off) ps[t] += u;
        __syncthreads();
    }
    if (t < NSCB) bsum[t] = ps[t] - v;   // exclusive
}

__global__ __launch_bounds__(256) void k_bout(const int* __restrict__ cnt,
                                              const int* __restrict__ bsum,
                                              int* __restrict__ rowstart) {
    __shared__ int ps[256];
    int t = threadIdx.x;
    int idx = blockIdx.x * 256 + t;
    int v = (idx < NND) ? cnt[idx] : 0;
    ps[t] = v;
    __syncthreads();
    for (int off = 1; off < 256; off <<= 1) {
        int u = 0;
        if (t >= off) u = ps[t - off];
        __syncthreads();
        if (t >= off) ps[t] += u;
        __syncthreads();
    }
    int boff = bsum[blockIdx.x];
    if (idx < NND) rowstart[idx] = boff + ps[t] - v;   // exclusive
    if (idx == NND - 1) rowstart[NND] = boff + ps[t];  // == NE
}

__global__ void k_fill(const int* __restrict__ ei, const int* __restrict__ rowstart,
                       int* __restrict__ cursor, int* __restrict__ adj) {
    int e = blockIdx.x * 256 + threadIdx.x;
    if (e >= NE) return;
    int s = ei[e], d = ei[NE + e];
    int pos = atomicAdd(&cursor[d], 1);
    adj[rowstart[d] + pos] = s;
}

// ---------------------------------------------------------------- MFMA GEMM
// C[M x Nc] = A[M x 128] @ B[128 x Nc] + bias, split-bf16 (3 MFMAs / tile).
// v2: B-frags loaded DIRECT from global to registers (B is 256KB, L2-resident,
// per-lane 16B loads in exact frag layout) -- no Bs LDS staging. LDS drops
// 55.3 -> 36.9 KB => 4 blocks/CU (was 2), doubling staging latency cover.
// A given as hi/lo bf16 [M][128]; B TRANSPOSED n-major hi/lo [Nc][128].
// 256 thr, tile 128x64, 4 waves: mw = w&1 -> 64 rows, nw = w>>1 -> 32 cols.
__global__ __launch_bounds__(256) void k_gemm_mfma(
    const unsigned short* __restrict__ Ahi, const unsigned short* __restrict__ Alo,
    const unsigned short* __restrict__ Bhi, const unsigned short* __restrict__ Blo,
    const float* __restrict__ bias, float* __restrict__ C,
    int M, int Nc)
{
    __shared__ unsigned short As_hi[128][72];
    __shared__ unsigned short As_lo[128][72];

    const int tid  = threadIdx.x;
    const int lane = tid & 63, wave = tid >> 6;
    const int mw = wave & 1, nw = wave >> 1;
    const int l15 = lane & 15, quad = lane >> 4;
    const int rowBase = blockIdx.x * 128;
    const int colBase = blockIdx.y * 64;

    f32x4 acc[4][2] = {};

    for (int kc = 0; kc < 128; kc += 64) {
        // B-frags direct from global (issued first; drained by the barrier)
        s16x8 bh[2][2], bl[2][2];   // [ns][kq]
        #pragma unroll
        for (int ns = 0; ns < 2; ++ns) {
            int gn = colBase + nw * 32 + ns * 16 + l15;
            #pragma unroll
            for (int kq = 0; kq < 2; ++kq) {
                bh[ns][kq] = *(const s16x8*)&Bhi[(size_t)gn * 128 + kc + kq * 32 + quad * 8];
                bl[ns][kq] = *(const s16x8*)&Blo[(size_t)gn * 128 + kc + kq * 32 + quad * 8];
            }
        }

        // stage A (128 rows x 64 k), 16B copies
        int lr = tid >> 3;            // 0..31
        int ko = (tid & 7) * 8;       // 0..56
        #pragma unroll
        for (int i = 0; i < 4; ++i) {
            int row = lr + i * 32;
            int g = rowBase + row;
            uint4 vh = make_uint4(0, 0, 0, 0), vl = make_uint4(0, 0, 0, 0);
            if (g < M) {
                vh = *(const uint4*)&Ahi[(size_t)g * 128 + kc + ko];
                vl = *(const uint4*)&Alo[(size_t)g * 128 + kc + ko];
            }
            *(uint4*)&As_hi[row][ko] = vh;
            *(uint4*)&As_lo[row][ko] = vl;
        }
        __syncthreads();

        #pragma unroll
        for (int kq = 0; kq < 2; ++kq) {
            int kof = kq * 32 + quad * 8;
            s16x8 ah[4], al[4];
            #pragma unroll
            for (int ms = 0; ms < 4; ++ms) {
                int r = mw * 64 + ms * 16 + l15;
                ah[ms] = *(const s16x8*)&As_hi[r][kof];
                al[ms] = *(const s16x8*)&As_lo[r][kof];
            }
            #pragma unroll
            for (int ms = 0; ms < 4; ++ms)
                #pragma unroll
                for (int ns = 0; ns < 2; ++ns)
                    acc[ms][ns] = __builtin_amdgcn_mfma_f32_16x16x32_bf16(ah[ms], bh[ns][kq], acc[ms][ns], 0, 0, 0);
            #pragma unroll
            for (int ms = 0; ms < 4; ++ms)
                #pragma unroll
                for (int ns = 0; ns < 2; ++ns)
                    acc[ms][ns] = __builtin_amdgcn_mfma_f32_16x16x32_bf16(al[ms], bh[ns][kq], acc[ms][ns], 0, 0, 0);
            #pragma unroll
            for (int ms = 0; ms < 4; ++ms)
                #pragma unroll
                for (int ns = 0; ns < 2; ++ns)
                    acc[ms][ns] = __builtin_amdgcn_mfma_f32_16x16x32_bf16(ah[ms], bl[ns][kq], acc[ms][ns], 0, 0, 0);
        }
        __syncthreads();
    }

    // epilogue: C/D layout col=lane&15, row=quad*4+reg
    #pragma unroll
    for (int ns = 0; ns < 2; ++ns) {
        int col = colBase + nw * 32 + ns * 16 + l15;
        float bv = bias ? bias[col] : 0.f;
        #pragma unroll
        for (int ms = 0; ms < 4; ++ms) {
            int row0 = rowBase + mw * 64 + ms * 16 + quad * 4;
            #pragma unroll
            for (int r = 0; r < 4; ++r) {
                int row = row0 + r;
                if (row < M) C[(size_t)row * Nc + col] = acc[ms][ns][r] + bv;
            }
        }
    }
}

// Variant: A is raw fp32 (the input x); split-bf16 conversion fused into the
// LDS staging (replaces the separate k_cvt pass).
__global__ __launch_bounds__(256) void k_gemm_mfma_xa(
    const float* __restrict__ X,
    const unsigned short* __restrict__ Bhi, const unsigned short* __restrict__ Blo,
    const float* __restrict__ bias, float* __restrict__ C,
    int M, int Nc)
{
    __shared__ unsigned short As_hi[128][72];
    __shared__ unsigned short As_lo[128][72];

    const int tid  = threadIdx.x;
    const int lane = tid & 63, wave = tid >> 6;
    const int mw = wave & 1, nw = wave >> 1;
    const int l15 = lane & 15, quad = lane >> 4;
    const int rowBase = blockIdx.x * 128;
    const int colBase = blockIdx.y * 64;

    f32x4 acc[4][2] = {};

    for (int kc = 0; kc < 128; kc += 64) {
        s16x8 bh[2][2], bl[2][2];
        #pragma unroll
        for (int ns = 0; ns < 2; ++ns) {
            int gn = colBase + nw * 32 + ns * 16 + l15;
            #pragma unroll
            for (int kq = 0; kq < 2; ++kq) {
                bh[ns][kq] = *(const s16x8*)&Bhi[(size_t)gn * 128 + kc + kq * 32 + quad * 8];
                bl[ns][kq] = *(const s16x8*)&Blo[(size_t)gn * 128 + kc + kq * 32 + quad * 8];
            }
        }

        // stage A: fp32 -> split-bf16 on the fly (8 floats per thread-chunk)
        int lr = tid >> 3;
        int ko = (tid & 7) * 8;
        #pragma unroll
        for (int i = 0; i < 4; ++i) {
            int row = lr + i * 32;
            int g = rowBase + row;
            unsigned short hx[8], lx[8];
            if (g < M) {
                float4 v0 = *(const float4*)&X[(size_t)g * 128 + kc + ko];
                float4 v1 = *(const float4*)&X[(size_t)g * 128 + kc + ko + 4];
                const float vv[8] = {v0.x, v0.y, v0.z, v0.w, v1.x, v1.y, v1.z, v1.w};
                #pragma unroll
                for (int e = 0; e < 8; ++e) {
                    hx[e] = f2bf(vv[e]);
                    lx[e] = f2bf(vv[e] - bf2f(hx[e]));
                }
            } else {
                #pragma unroll
                for (int e = 0; e < 8; ++e) { hx[e] = 0; lx[e] = 0; }
            }
            *(uint4*)&As_hi[row][ko] = *(const uint4*)hx;
            *(uint4*)&As_lo[row][ko] = *(const uint4*)lx;
        }
        __syncthreads();

        #pragma unroll
        for (int kq = 0; kq < 2; ++kq) {
            int kof = kq * 32 + quad * 8;
            s16x8 ah[4], al[4];
            #pragma unroll
            for (int ms = 0; ms < 4; ++ms) {
                int r = mw * 64 + ms * 16 + l15;
                ah[ms] = *(const s16x8*)&As_hi[r][kof];
                al[ms] = *(const s16x8*)&As_lo[r][kof];
            }
            #pragma unroll
            for (int ms = 0; ms < 4; ++ms)
                #pragma unroll
                for (int ns = 0; ns < 2; ++ns)
                    acc[ms][ns] = __builtin_amdgcn_mfma_f32_16x16x32_bf16(ah[ms], bh[ns][kq], acc[ms][ns], 0, 0, 0);
            #pragma unroll
            for (int ms = 0; ms < 4; ++ms)
                #pragma unroll
                for (int ns = 0; ns < 2; ++ns)
                    acc[ms][ns] = __builtin_amdgcn_mfma_f32_16x16x32_bf16(al[ms], bh[ns][kq], acc[ms][ns], 0, 0, 0);
            #pragma unroll
            for (int ms = 0; ms < 4; ++ms)
                #pragma unroll
                for (int ns = 0; ns < 2; ++ns)
                    acc[ms][ns] = __builtin_amdgcn_mfma_f32_16x16x32_bf16(ah[ms], bl[ns][kq], acc[ms][ns], 0, 0, 0);
        }
        __syncthreads();
    }

    #pragma unroll
    for (int ns = 0; ns < 2; ++ns) {
        int col = colBase + nw * 32 + ns * 16 + l15;
        float bv = bias ? bias[col] : 0.f;
        #pragma unroll
        for (int ms = 0; ms < 4; ++ms) {
            int row0 = rowBase + mw * 64 + ms * 16 + quad * 4;
            #pragma unroll
            for (int r = 0; r < 4; ++r) {
                int row = row0 + r;
                if (row < M) C[(size_t)row * Nc + col] = acc[ms][ns][r] + bv;
            }
        }
    }
}

// ---------------------------------------------------------------- GCN gather
// One wave per node; lane owns 2 cols (float2). agg = dn*(sum_s h[s]*ds + h[n]*dn),
// fused bias + relu + split-bf16 output (feeds the next MFMA GEMM directly).
// NOTE: hi/lo output MUST NOT alias h (blocks read arbitrary h rows).
__global__ __launch_bounds__(256) void k_gather(
    const int* __restrict__ rowstart, const int* __restrict__ adj,
    const float* __restrict__ h, const float* __restrict__ dinv,
    const float* __restrict__ bias,
    unsigned short* __restrict__ hi, unsigned short* __restrict__ lo)
{
    const int n    = blockIdx.x * 4 + (threadIdx.x >> 6);   // grid exactly NND/4
    const int lane = threadIdx.x & 63;
    const int r0 = rowstart[n], r1 = rowstart[n + 1];
    const float dn = dinv[n];

    float2 hv = *(const float2*)&h[(size_t)n * 128 + 2 * lane];
    float2 acc;
    acc.x = hv.x * dn;
    acc.y = hv.y * dn;
    for (int i = r0; i < r1; ++i) {
        int s = adj[i];                 // wave-uniform broadcast
        float ds = dinv[s];
        float2 v = *(const float2*)&h[(size_t)s * 128 + 2 * lane];
        acc.x += v.x * ds;
        acc.y += v.y * ds;
    }
    float2 bb = *(const float2*)&bias[2 * lane];
    float vx = fmaxf(acc.x * dn + bb.x, 0.f);
    float vy = fmaxf(acc.y * dn + bb.y, 0.f);
    ushort2 ho, lo2;
    ho.x = f2bf(vx); lo2.x = f2bf(vx - bf2f(ho.x));
    ho.y = f2bf(vy); lo2.y = f2bf(vy - bf2f(ho.y));
    *(ushort2*)&hi[(size_t)n * 128 + 2 * lane] = ho;
    *(ushort2*)&lo[(size_t)n * 128 + 2 * lane] = lo2;
}

// ---------------------------------------------------------------- prep kernels
// GCN weight W [128(k)][128(n)] fp32 -> transposed n-major split-bf16 [n][k]
__global__ void k_prep_gcnw(const float* __restrict__ W,
                            unsigned short* __restrict__ hi, unsigned short* __restrict__ lo) {
    int t = blockIdx.x * 256 + threadIdx.x;
    if (t >= 16384) return;
    int k = t >> 7, n = t & 127;
    float v = W[t];
    unsigned short h = f2bf(v);
    hi[n * 128 + k] = h;
    lo[n * 128 + k] = f2bf(v - bf2f(h));
}

// LSTM prep: both w_ih and w_hh [512(r=g*128+j)][128(k)] -> packed-transposed
// split-bf16 wT[p=j*4+g][k]; bias -> bp[p] = b_ih + b_hh.
__global__ void k_prep_lstm(const float* __restrict__ w_ih, const float* __restrict__ w_hh,
                            const float* __restrict__ b_ih, const float* __restrict__ b_hh,
                            unsigned short* __restrict__ ih_hi, unsigned short* __restrict__ ih_lo,
                            unsigned short* __restrict__ hh_hi, unsigned short* __restrict__ hh_lo,
                            float* __restrict__ bp)
{
    int t = blockIdx.x * 256 + threadIdx.x;
    if (t < 65536) {
        int r = t >> 7, k = t & 127;
        int g = r >> 7, j = r & 127;
        int p = (j << 2) + g;
        float v = w_ih[t];
        unsigned short h = f2bf(v);
        ih_hi[p * 128 + k] = h;
        ih_lo[p * 128 + k] = f2bf(v - bf2f(h));
    } else if (t < 131072) {
        int t2 = t - 65536;
        int r = t2 >> 7, k = t2 & 127;
        int g = r >> 7, j = r & 127;
        int p = (j << 2) + g;
        float v = w_hh[t2];
        unsigned short h = f2bf(v);
        hh_hi[p * 128 + k] = h;
        hh_lo[p * 128 + k] = f2bf(v - bf2f(h));
    } else if (t < 131584) {
        int r = t - 131072;   // 0..511
        int g = r >> 7, j = r & 127;
        bp[(j << 2) + g] = b_ih[r] + b_hh[r];
    }
}

// ---------------------------------------------------------------- LSTM recurrence
// v9: ONE barrier per step via intra-wave phase-2.
// Wave w owns gate-cols [64w, 64w+64). Its quad-0 lanes hold ALL used P rows
// (rows 0..3 = the 4 sequences). Phase-2 is remapped so lane l of wave w
// handles (b = l>>4, j = 16w + (l&15)) -- fed ONLY by wave w's accumulators
// through a per-wave LDS patch (intra-wave exchange: lgkmcnt, no barrier).
// The only cross-wave data is Ah/Al (next step's A operand) -> 1 barrier/step.
__global__ __launch_bounds__(512, 2) void k_lstm(
    const float* __restrict__ G,            // (NB*TSEQ) x 512, gate-packed cols
    const unsigned short* __restrict__ Whi, // 512 x 128, packed-transposed hi
    const unsigned short* __restrict__ Wlo, // lo
    unsigned short* __restrict__ Hhi,       // (NB*TSEQ) x 128 bf16-hi, or nullptr
    unsigned short* __restrict__ Hlo,       // bf16-lo, or nullptr
    float* __restrict__ Hlast)              // NB x 128 fp32 (last step), or nullptr
{
    const int tid  = threadIdx.x;
    const int lane = tid & 63, wave = tid >> 6;   // 8 waves
    const int l15  = lane & 15, quad = lane >> 4;
    const int b0   = blockIdx.x * SB;

    __shared__ unsigned short Ah[16 * AHS];  // h hi (rows SB..15 stay zero)
    __shared__ unsigned short Al[16 * AHS];  // h lo
    __shared__ float partw[8][4][72];        // per-wave P patch [wave][b][col in wave]

    // weight fragments: wave owns n-tiles nt0..nt0+3 (n = p = j*4+gate)
    const int nt0 = wave * 4;
    s16x8 bh[4][4], bl[4][4];   // [nt][ks]
    #pragma unroll
    for (int nt = 0; nt < 4; ++nt) {
        int p = (nt0 + nt) * 16 + l15;
        #pragma unroll
        for (int ks = 0; ks < 4; ++ks) {
            bh[nt][ks] = *(const s16x8*)&Whi[(size_t)p * 128 + ks * 32 + quad * 8];
            bl[nt][ks] = *(const s16x8*)&Wlo[(size_t)p * 128 + ks * 32 + quad * 8];
        }
    }

    for (int i = tid; i < 16 * AHS; i += 512) { Ah[i] = 0; Al[i] = 0; }

    // phase-2 mapping: lane l of wave w -> (b2, j) with j owned by wave w
    const int b2 = lane >> 4;              // 0..3
    const int jj = wave * 16 + l15;        // hidden unit this lane updates
    const int bg = b0 + b2;                // sequence index (NB % SB == 0)
    float c = 0.f;
    float hn_last = 0.f;
    __syncthreads();

    const float* gbase = &G[((size_t)bg * TSEQ) * 512 + (jj << 2)];

    for (int step = 0; step < TSEQ; ++step) {
        // gate input for phase 2 (issued early; covered by phase-1 MFMA time,
        // no intervening barrier to force-drain it)
        const float4 gv = *(const float4*)&gbase[(size_t)step * 512];

        // phase 1: MFMA  P = h @ W^T  (split bf16, lo*lo dropped)
        f32x4 acc[4] = {};
        #pragma unroll
        for (int ks = 0; ks < 4; ++ks) {
            s16x8 ah = *(const s16x8*)&Ah[l15 * AHS + ks * 32 + quad * 8];
            s16x8 al = *(const s16x8*)&Al[l15 * AHS + ks * 32 + quad * 8];
            #pragma unroll
            for (int nt = 0; nt < 4; ++nt) {
                acc[nt] = __builtin_amdgcn_mfma_f32_16x16x32_bf16(ah, bh[nt][ks], acc[nt], 0, 0, 0);
                acc[nt] = __builtin_amdgcn_mfma_f32_16x16x32_bf16(al, bh[nt][ks], acc[nt], 0, 0, 0);
                acc[nt] = __builtin_amdgcn_mfma_f32_16x16x32_bf16(ah, bl[nt][ks], acc[nt], 0, 0, 0);
            }
        }

        // intra-wave exchange: quad-0 lanes hold rows 0..3 (the real seqs)
        if (quad == 0) {
            #pragma unroll
            for (int nt = 0; nt < 4; ++nt)
                #pragma unroll
                for (int r = 0; r < 4; ++r)
                    partw[wave][r][nt * 16 + l15] = acc[nt][r];
        }
        // same-wave producer/consumer: compiler inserts lgkmcnt wait, no barrier

        // phase 2: LSTM cell for (b2, jj); reads this wave's own patch
        {
            float4 pa = *(const float4*)&partw[wave][b2][l15 * 4];
            float xi = pa.x + gv.x;
            float xf = pa.y + gv.y;
            float xg = pa.z + gv.z;
            float xo = pa.w + gv.w;
            float ii = sigf(xi), ff = sigf(xf), gg = tanhfast(xg), oo = sigf(xo);
            float cn = ff * c + ii * gg;
            c = cn;
            float hn = oo * tanhfast(cn);
            hn_last = hn;
            unsigned short hh = f2bf(hn);
            unsigned short hl = f2bf(hn - bf2f(hh));
            Ah[b2 * AHS + jj] = hh;
            Al[b2 * AHS + jj] = hl;
            if (Hhi) {
                Hhi[((size_t)bg * TSEQ + step) * 128 + jj] = hh;
                Hlo[((size_t)bg * TSEQ + step) * 128 + jj] = hl;
            }
        }
        // single barrier: Ah/Al writes must be visible to all waves' phase-1
        __syncthreads();
    }

    if (Hlast)
        Hlast[(size_t)bg * 128 + jj] = hn_last;
}

// ---------------------------------------------------------------- FC head
// last: NB x 128 fp32 (compact last-step h)
__global__ __launch_bounds__(256) void k_fc(
    const float* __restrict__ last, const float* __restrict__ fcw,
    const float* __restrict__ fcb, float* __restrict__ out)
{
    int b    = blockIdx.x * 4 + (threadIdx.x >> 6);
    int lane = threadIdx.x & 63;
    const float* row = &last[(size_t)b * 128];
    float v = row[lane] * fcw[lane] + row[lane + 64] * fcw[lane + 64];
    #pragma unroll
    for (int off = 32; off > 0; off >>= 1)
        v += __shfl_down(v, off);
    if (lane == 0) out[b] = v + fcb[0];
}

// ---------------------------------------------------------------- launch
extern "C" void kernel_launch(void* const* d_in, const int* in_sizes, int n_in,
                              void* d_out, int out_size, void* d_ws, size_t ws_size,
                              hipStream_t stream)
{
    const float* x    = (const float*)d_in[0];
    const int*   ei   = (const int*)d_in[1];
    const float* W1   = (const float*)d_in[3];
    const float* b1   = (const float*)d_in[4];
    const float* W2   = (const float*)d_in[5];
    const float* b2   = (const float*)d_in[6];
    const float* fcw  = (const float*)d_in[7];
    const float* fcb  = (const float*)d_in[8];
    const float* wih0 = (const float*)d_in[9];
    const float* whh0 = (const float*)d_in[10];
    const float* bih0 = (const float*)d_in[11];
    const float* bhh0 = (const float*)d_in[12];
    const float* wih1 = (const float*)d_in[13];
    const float* whh1 = (const float*)d_in[14];
    const float* bih1 = (const float*)d_in[15];
    const float* bhh1 = (const float*)d_in[16];
    float* out = (float*)d_out;

    char* ws = (char*)d_ws;
    // ---- persistent regions
    unsigned short* shi = (unsigned short*)(ws + 0);          // 12.8 MB
    unsigned short* slo = (unsigned short*)(ws + 12800000);   // 12.8 MB (ends 25.6M)
    float* bufX = (float*)(ws + 25600000);                    // 0.512 MB (NB x 128; ends 26.2M)
    float* bufG = (float*)(ws + 51200000);                    // 102.4 MB (ends 153.6M)

    // ---- GCN-phase regions (inside bufG, dead before gate GEMM writes bufG)
    unsigned short* xhi = (unsigned short*)(ws + 51200000);   // 12.8 MB
    unsigned short* xlo = (unsigned short*)(ws + 64000000);   // 12.8 MB
    float* bufHg  = (float*)(ws + 76800000);                  // 25.6 MB (ends 102.4M)
    int* cnt      = (int*)(ws + 102400000);
    int* rowstart = (int*)(ws + 102604800);
    int* cursor   = (int*)(ws + 102809600);
    int* adj      = (int*)(ws + 103014400);                   // 2.4 MB (ends 105.42M)
    int* bsum     = (int*)(ws + 105420800);                   // NSCB ints

    float* dinv = (float*)(ws + 153600000);
    float* bp0  = (float*)(ws + 153800192);
    float* bp1  = (float*)(ws + 153802240);
    unsigned short* w1t_hi   = (unsigned short*)(ws + 153804288);
    unsigned short* w1t_lo   = (unsigned short*)(ws + 153837056);
    unsigned short* w2t_hi   = (unsigned short*)(ws + 153869824);
    unsigned short* w2t_lo   = (unsigned short*)(ws + 153902592);
    unsigned short* wpih0_hi = (unsigned short*)(ws + 153935360);
    unsigned short* wpih0_lo = (unsigned short*)(ws + 154066432);
    unsigned short* wpih1_hi = (unsigned short*)(ws + 154197504);
    unsigned short* wpih1_lo = (unsigned short*)(ws + 154328576);
    unsigned short* wphh0_hi = (unsigned short*)(ws + 154459648);
    unsigned short* wphh0_lo = (unsigned short*)(ws + 154590720);
    unsigned short* wphh1_hi = (unsigned short*)(ws + 154721792);
    unsigned short* wphh1_lo = (unsigned short*)(ws + 154852864);

    // ---- CSR build + dinv (multi-block scan)
    hipMemsetAsync(cnt, 0, NND * sizeof(int), stream);
    hipMemsetAsync(cursor, 0, NND * sizeof(int), stream);
    k_count<<<(NE + 255) / 256, 256, 0, stream>>>(ei, cnt);
    k_bsum<<<NSCB, 256, 0, stream>>>(cnt, bsum);
    k_bscan<<<1, 256, 0, stream>>>(bsum);
    k_bout<<<NSCB, 256, 0, stream>>>(cnt, bsum, rowstart);
    k_dinv<<<(NND + 255) / 256, 256, 0, stream>>>(cnt, dinv);
    k_fill<<<(NE + 255) / 256, 256, 0, stream>>>(ei, rowstart, cursor, adj);

    // ---- weight prep
    k_prep_gcnw<<<64, 256, 0, stream>>>(W1, w1t_hi, w1t_lo);
    k_prep_gcnw<<<64, 256, 0, stream>>>(W2, w2t_hi, w2t_lo);
    k_prep_lstm<<<514, 256, 0, stream>>>(wih0, whh0, bih0, bhh0,
                                         wpih0_hi, wpih0_lo, wphh0_hi, wphh0_lo, bp0);
    k_prep_lstm<<<514, 256, 0, stream>>>(wih1, whh1, bih1, bhh1,
                                         wpih1_hi, wpih1_lo, wphh1_hi, wphh1_lo, bp1);

    dim3 gH(391, 2);   // 128-col GEMMs (ceil(50000/128)=391)
    dim3 gG(391, 8);   // 512-col GEMMs

    // ---- GCN layer 1 (fp32 A, convert-on-stage; k_cvt eliminated)
    k_gemm_mfma_xa<<<gH, 256, 0, stream>>>(x, w1t_hi, w1t_lo, nullptr, bufHg, NND, 128);
    k_gather<<<NND / 4, 256, 0, stream>>>(rowstart, adj, bufHg, dinv, b1, xhi, xlo);

    // ---- GCN layer 2 (gather writes shi/slo @0-25.6M, disjoint from bufHg)
    k_gemm_mfma<<<gH, 256, 0, stream>>>(xhi, xlo, w2t_hi, w2t_lo, nullptr, bufHg, NND, 128);
    k_gather<<<NND / 4, 256, 0, stream>>>(rowstart, adj, bufHg, dinv, b2, shi, slo);

    // ---- LSTM layer 0: gate GEMM + MFMA recurrence (emits split-bf16 seq0 -> shi/slo)
    k_gemm_mfma<<<gG, 256, 0, stream>>>(shi, slo, wpih0_hi, wpih0_lo, bp0, bufG, NND, 512);
    k_lstm<<<NB / SB, 512, 0, stream>>>(bufG, wphh0_hi, wphh0_lo, shi, slo, nullptr);

    // ---- LSTM layer 1 (reads gates; emits only compact last-step fp32 -> bufX)
    k_gemm_mfma<<<gG, 256, 0, stream>>>(shi, slo, wpih1_hi, wpih1_lo, bp1, bufG, NND, 512);
    k_lstm<<<NB / SB, 512, 0, stream>>>(bufG, wphh1_hi, wphh1_lo, nullptr, nullptr, bufX);

    // ---- FC head
    k_fc<<<NB / 4, 256, 0, stream>>>(bufX, fcw, fcb, out);
}